// Round 1
// baseline (1202.274 us; speedup 1.0000x reference)
//
#include <hip/hip_runtime.h>
#include <math.h>

#define NB    1024
#define NC    62
#define NBAND 5
#define NOUT  16
#define NHID  10

// =====================================================================
// Kernel A: gate-cancelled SPD.
//   _gate: relu(g*x) = g*relu(x) since g=softmax>0.
//   _spd:  cov/trace cancels g^2 and 1/(c-1), so
//   com[b,k] = 0.5*(N(relu(pcc_t)) + N(relu(A))) + 1e-5*I,
//   N(X) = Xc^T Xc / ||Xc||_F^2,  Xc = X - rowmean(X).
//   conv_w / conv_b / the softmax gate are dead.
// Thread map: tid -> (j = tid>>2, q = tid&3); thread owns G[j][q*16 .. q*16+15].
// =====================================================================
__global__ __launch_bounds__(256) void k_spd(
    const float* __restrict__ pcc, const float* __restrict__ Aadj,
    float* __restrict__ com) {
  const int bk = blockIdx.x;               // 0..5119
  const int b = bk / NBAND, k = bk % NBAND;
  __shared__ __align__(16) float Xc[NC * 64];   // stride 64, cols 62/63 zero
  __shared__ float red[256];
  __shared__ float rowmean[64];
  const int tid = threadIdx.x;
  const int j = tid >> 2, q = tid & 3;

  float acc0[16], acc1[16];

  auto process = [&](int src, float (&acc)[16]) -> float {
    // load relu(X) into LDS (zero-padded cols 62,63)
    for (int t = tid; t < NC * 64; t += 256) {
      const int i = t >> 6, jj = t & 63;
      float v = 0.f;
      if (jj < NC) {
        v = (src == 0) ? pcc[((b * NC + i) * NC + jj) * NBAND + k]   // x_f[b,k,i,j]=pcc[b,i,j,k]
                       : Aadj[((b * NBAND + k) * NC + i) * NC + jj]; // x_s[b,k,i,j]
        v = fmaxf(v, 0.f);
      }
      Xc[t] = v;
    }
    __syncthreads();
    // row means (4 partials per row)
    float ps = 0.f;
    if (j < NC) {
#pragma unroll
      for (int u = 0; u < 16; ++u) ps += Xc[j * 64 + q * 16 + u];  // pad cols are 0
    }
    red[tid] = ps;
    __syncthreads();
    if (tid < NC)
      rowmean[tid] = (red[tid * 4] + red[tid * 4 + 1] + red[tid * 4 + 2] + red[tid * 4 + 3]) * (1.f / NC);
    __syncthreads();
    // subtract mean in place + Frobenius^2 (= trace of X^T X)
    float sq = 0.f;
    if (j < NC) {
      const float m = rowmean[j];
#pragma unroll
      for (int u = 0; u < 16; ++u) {
        const int l = q * 16 + u;
        if (l < NC) {
          const float v = Xc[j * 64 + l] - m;
          Xc[j * 64 + l] = v;
          sq += v * v;
        }
      }
    }
    red[tid] = sq;
    __syncthreads();
    for (int s = 128; s > 0; s >>= 1) {
      if (tid < s) red[tid] += red[tid + s];
      __syncthreads();
    }
    const float tra = red[0];
    // SYRK: G[j][l] = sum_i Xc[i][j]*Xc[i][l]
#pragma unroll
    for (int u = 0; u < 16; ++u) acc[u] = 0.f;
    for (int i = 0; i < NC; ++i) {
      const float xj = Xc[i * 64 + j];  // broadcast within 4-lane groups
      const float4 v0 = *reinterpret_cast<const float4*>(&Xc[i * 64 + q * 16 + 0]);
      const float4 v1 = *reinterpret_cast<const float4*>(&Xc[i * 64 + q * 16 + 4]);
      const float4 v2 = *reinterpret_cast<const float4*>(&Xc[i * 64 + q * 16 + 8]);
      const float4 v3 = *reinterpret_cast<const float4*>(&Xc[i * 64 + q * 16 + 12]);
      acc[0]  += xj * v0.x; acc[1]  += xj * v0.y; acc[2]  += xj * v0.z; acc[3]  += xj * v0.w;
      acc[4]  += xj * v1.x; acc[5]  += xj * v1.y; acc[6]  += xj * v1.z; acc[7]  += xj * v1.w;
      acc[8]  += xj * v2.x; acc[9]  += xj * v2.y; acc[10] += xj * v2.z; acc[11] += xj * v2.w;
      acc[12] += xj * v3.x; acc[13] += xj * v3.y; acc[14] += xj * v3.z; acc[15] += xj * v3.w;
    }
    __syncthreads();   // Xc/red reuse by next source
    return tra;
  };

  const float tra0 = process(0, acc0);
  const float tra1 = process(1, acc1);

  if (j < NC) {
    const float s0 = 0.5f / tra0, s1 = 0.5f / tra1;
    const int base = (bk * NC + j) * NC;
#pragma unroll
    for (int u = 0; u < 16; ++u) {
      const int l = q * 16 + u;
      if (l < NC) {
        float v = acc0[u] * s0 + acc1[u] * s1;
        if (l == j) v += 1e-5f;
        com[base + l] = v;
      }
    }
  }
}

// =====================================================================
// Kernel B: sigmoid branch + band attention, one block per (b, branch).
//   z[b,k,i,o] = sigmoid(cw[k]*(com_row . lw[o,:]) + cb[k]*rowsum(lw[o]) + lb[o])
//   score[b,k,i] = att_w2 . tanh(att_w1 @ z_row + att_b1); softmax over k;
//   out[b,i,c] = sum_k beta[k,i]*z[k,i,c]
// lw row held in 62 registers per lane (lane = o).
// =====================================================================
__global__ __launch_bounds__(256) void k_branch_attn(
    const float* __restrict__ com,
    const float* __restrict__ hconv_w, const float* __restrict__ hconv_b,
    const float* __restrict__ hlin_w,  const float* __restrict__ hlin_b,
    const float* __restrict__ econv_w, const float* __restrict__ econv_b,
    const float* __restrict__ elin_w,  const float* __restrict__ elin_b,
    const float* __restrict__ att_w1,  const float* __restrict__ att_b1,
    const float* __restrict__ att_w2,
    float* __restrict__ hiddenO, float* __restrict__ essentialO) {
  const int b = blockIdx.x >> 1, br = blockIdx.x & 1;
  const float* __restrict__ cw = br ? econv_w : hconv_w;
  const float* __restrict__ cb = br ? econv_b : hconv_b;
  const float* __restrict__ lw = br ? elin_w : hlin_w;
  const float* __restrict__ lb = br ? elin_b : hlin_b;
  float* __restrict__ outp = br ? essentialO : hiddenO;

  __shared__ float zall[310 * NC];     // 76.9 KB
  __shared__ float w1S[NHID * NC];
  __shared__ float score[312];
  __shared__ float beta[312];
  __shared__ float lbS[64];
  __shared__ float b1S[16], w2S[16], cwS[8], cbS[8];
  __shared__ float crowS[4][64];

  const int tid = threadIdx.x;
  const int wave = tid >> 6, lane = tid & 63;

  for (int t = tid; t < NHID * NC; t += 256) w1S[t] = att_w1[t];
  if (tid < NC) lbS[tid] = lb[tid];
  if (tid < NHID) { b1S[tid] = att_b1[tid]; w2S[tid] = att_w2[tid]; }
  if (tid < NBAND) { cwS[tid] = cw[tid]; cbS[tid] = cb[tid]; }

  // register copy of lin-weight row o = lane, plus its row sum
  float lwreg[NC];
  float rsum = 0.f;
  {
    const int o = (lane < NC) ? lane : (NC - 1);
#pragma unroll
    for (int c = 0; c < NC; ++c) { lwreg[c] = lw[o * NC + c]; rsum += lwreg[c]; }
  }
  __syncthreads();

  // 310 rows (k,i), 4 waves, uniform trip count for block barriers
  for (int it = 0; it < 78; ++it) {
    const int r = wave + it * 4;
    const bool active = (r < 310);
    const int rr = active ? r : 309;
    const int k = rr / NC, i = rr % NC;
    if (active && lane < NC)
      crowS[wave][lane] = com[((b * NBAND + k) * NC + i) * NC + lane];
    __syncthreads();
    if (active && lane < NC) {
      float acc = 0.f;
#pragma unroll
      for (int c = 0; c < NC; ++c) acc += crowS[wave][c] * lwreg[c];
      float z = cwS[k] * acc + cbS[k] * rsum + lbS[lane];
      z = 1.f / (1.f + __expf(-z));
      zall[r * NC + lane] = z;
    }
    __syncthreads();
    if (active) {
      float part = 0.f;
      if (lane < NHID) {
        float a = b1S[lane];
        for (int c = 0; c < NC; ++c) a += zall[r * NC + c] * w1S[lane * NC + c];
        part = w2S[lane] * tanhf(a);
      }
#pragma unroll
      for (int off = 8; off > 0; off >>= 1) part += __shfl_down(part, off, 64);
      if (lane == 0) score[r] = part;
    }
  }
  __syncthreads();
  // softmax over k per i
  if (tid < NC) {
    const int i = tid;
    float m = -1e30f;
#pragma unroll
    for (int k = 0; k < NBAND; ++k) m = fmaxf(m, score[k * NC + i]);
    float e[NBAND], s = 0.f;
#pragma unroll
    for (int k = 0; k < NBAND; ++k) { e[k] = __expf(score[k * NC + i] - m); s += e[k]; }
    const float inv = 1.f / s;
#pragma unroll
    for (int k = 0; k < NBAND; ++k) beta[k * NC + i] = e[k] * inv;
  }
  __syncthreads();
  // weighted sum over bands
  for (int t = tid; t < NC * NC; t += 256) {
    const int i = t / NC, c = t % NC;
    float s = 0.f;
#pragma unroll
    for (int k = 0; k < NBAND; ++k) s += beta[k * NC + i] * zall[(k * NC + i) * NC + c];
    outp[b * (NC * NC) + t] = s;
  }
}

// =====================================================================
// Kernel C: Chebyshev GCN (both adjacencies, shared de@gc_w), feature,
// and the 992->62 FC. wnorm = exp(w)/exp(w) = 1 exactly (1-elem wpar);
// relu((h+e)/2) = (h+e)/2 since h,e >= 0.
// =====================================================================
__global__ __launch_bounds__(256) void k_cheb_fc(
    const float* __restrict__ de, const float* __restrict__ hidden,
    const float* __restrict__ essential, const float* __restrict__ gc_w,
    const float* __restrict__ gc_b, const float* __restrict__ fc_w,
    const float* __restrict__ fc_b, float* __restrict__ zmat) {
  const int b = blockIdx.x;
  __shared__ float hidS[NC * NC], essS[NC * NC];
  __shared__ float t0S[NC * NOUT], t1S[NC * NOUT];
  __shared__ float featS[NC * NOUT];
  __shared__ float deS[NC * NBAND];
  __shared__ float red2[256];
  const int tid = threadIdx.x;

  for (int t = tid; t < NC * NBAND; t += 256) deS[t] = de[b * NC * NBAND + t];
  for (int t = tid; t < NC * NC; t += 256) {
    hidS[t] = hidden[b * NC * NC + t];
    essS[t] = essential[b * NC * NC + t];
  }
  __syncthreads();
  // t0 = de@gc_w0 + gc_b0 ; t1 = de@gc_w1
  for (int t = tid; t < NC * NOUT; t += 256) {
    const int i = t / NOUT, f = t % NOUT;
    float a0 = gc_b[f];
    float a1 = 0.f;
#pragma unroll
    for (int qq = 0; qq < NBAND; ++qq) {
      const float d = deS[i * NBAND + qq];
      a0 += d * gc_w[qq * NOUT + f];
      a1 += d * gc_w[(NBAND + qq) * NOUT + f];
    }
    t0S[t] = a0;
    t1S[t] = a1;
  }
  __syncthreads();
  // feature = 0.5*(relu(t0 + H@t1 + gb1) + relu(t0 + E@t1 + gb1))
  for (int t = tid; t < NC * NOUT; t += 256) {
    const int i = t / NOUT, f = t % NOUT;
    float sh = 0.f, se = 0.f;
    for (int jj = 0; jj < NC; ++jj) {
      const float t1 = t1S[jj * NOUT + f];
      sh += hidS[i * NC + jj] * t1;
      se += essS[i * NC + jj] * t1;
    }
    const float gb1 = gc_b[NOUT + f];
    const float h = fmaxf(t0S[t] + sh + gb1, 0.f);
    const float e = fmaxf(t0S[t] + se + gb1, 0.f);
    featS[t] = 0.5f * (h + e);
  }
  __syncthreads();
  // z[n] = feat . fc_w[n,:] + fc_b[n]; 4 partials per n
  {
    const int n = tid >> 2, q = tid & 3;
    float p = 0.f;
    if (n < NC) {
      const float* fw = fc_w + n * (NC * NOUT) + q * 248;
      const float* fs = featS + q * 248;
      for (int m = 0; m < 248; ++m) p += fs[m] * fw[m];
    }
    red2[tid] = p;
    __syncthreads();
    if (tid < NC) {
      const float z = red2[tid * 4] + red2[tid * 4 + 1] + red2[tid * 4 + 2] + red2[tid * 4 + 3] + fc_b[tid];
      zmat[b * NC + tid] = z;
    }
  }
}

// =====================================================================
// Kernel D1: batch-norm statistics (training-mode batch stats, ddof=0),
// folded into scale/shift per feature.
// =====================================================================
__global__ __launch_bounds__(256) void k_bnstats(
    const float* __restrict__ zmat, const float* __restrict__ bn_g,
    const float* __restrict__ bn_b, float* __restrict__ bnp) {
  const int n = blockIdx.x;   // 0..61
  __shared__ float rs[256], rq[256];
  const int tid = threadIdx.x;
  float s = 0.f, sq = 0.f;
  for (int r = tid; r < NB; r += 256) {
    const float v = zmat[r * NC + n];
    s += v;
    sq += v * v;
  }
  rs[tid] = s; rq[tid] = sq;
  __syncthreads();
  for (int st = 128; st > 0; st >>= 1) {
    if (tid < st) { rs[tid] += rs[tid + st]; rq[tid] += rq[tid + st]; }
    __syncthreads();
  }
  if (tid == 0) {
    const float mean = rs[0] * (1.f / NB);
    const float var = rq[0] * (1.f / NB) - mean * mean;
    const float sc = bn_g[n] * rsqrtf(var + 1e-5f);
    bnp[2 * n] = sc;
    bnp[2 * n + 1] = bn_b[n] - mean * sc;
  }
}

// =====================================================================
// Kernel D2: apply BN + sigmoid -> output1; 62->2 FC -> output.
// =====================================================================
__global__ __launch_bounds__(64) void k_bn_out(
    const float* __restrict__ zmat, const float* __restrict__ bnp,
    const float* __restrict__ fc4_w, const float* __restrict__ fc4_b,
    float* __restrict__ out) {
  const int b = blockIdx.x;
  const int lane = threadIdx.x;
  float o1 = 0.f;
  if (lane < NC) {
    float z = zmat[b * NC + lane];
    z = z * bnp[2 * lane] + bnp[2 * lane + 1];
    o1 = 1.f / (1.f + __expf(-z));
    out[b * NC + lane] = o1;
  }
  float p0 = (lane < NC) ? o1 * fc4_w[lane] : 0.f;
  float p1 = (lane < NC) ? o1 * fc4_w[NC + lane] : 0.f;
#pragma unroll
  for (int off = 32; off > 0; off >>= 1) {
    p0 += __shfl_down(p0, off, 64);
    p1 += __shfl_down(p1, off, 64);
  }
  if (lane == 0) {
    out[NB * NC + b * 2 + 0] = p0 + fc4_b[0];
    out[NB * NC + b * 2 + 1] = p1 + fc4_b[1];
  }
}

extern "C" void kernel_launch(void* const* d_in, const int* in_sizes, int n_in,
                              void* d_out, int out_size, void* d_ws, size_t ws_size,
                              hipStream_t stream) {
  const float* de      = (const float*)d_in[0];
  const float* pcc     = (const float*)d_in[1];
  const float* Aadj    = (const float*)d_in[2];
  // d_in[3] conv_w, d_in[4] conv_b: dead (gate cancels in trace-normalized SPD)
  const float* hconv_w = (const float*)d_in[5];
  const float* hconv_b = (const float*)d_in[6];
  const float* hlin_w  = (const float*)d_in[7];
  const float* hlin_b  = (const float*)d_in[8];
  const float* econv_w = (const float*)d_in[9];
  const float* econv_b = (const float*)d_in[10];
  const float* elin_w  = (const float*)d_in[11];
  const float* elin_b  = (const float*)d_in[12];
  const float* att_w1  = (const float*)d_in[13];
  const float* att_b1  = (const float*)d_in[14];
  const float* att_w2  = (const float*)d_in[15];
  const float* gc_w    = (const float*)d_in[16];
  const float* gc_b    = (const float*)d_in[17];
  // d_in[18] wpar: wnorm = exp(w)/exp(w) = 1 exactly for 1-element wpar
  const float* fc_w    = (const float*)d_in[19];
  const float* fc_b    = (const float*)d_in[20];
  const float* bn_g    = (const float*)d_in[21];
  const float* bn_b    = (const float*)d_in[22];
  const float* fc4_w   = (const float*)d_in[23];
  const float* fc4_b   = (const float*)d_in[24];

  float* ws        = (float*)d_ws;
  float* com       = ws;                                 // 5120*3844   = 19,681,280
  float* hidden    = com + (size_t)NB * NBAND * NC * NC; // 1024*3844   =  3,936,256
  float* essential = hidden + (size_t)NB * NC * NC;
  float* zmat      = essential + (size_t)NB * NC * NC;   // 1024*62
  float* bnp       = zmat + (size_t)NB * NC;             // 124
  // total ~110.5 MB of workspace

  k_spd<<<NB * NBAND, 256, 0, stream>>>(pcc, Aadj, com);
  k_branch_attn<<<NB * 2, 256, 0, stream>>>(com,
      hconv_w, hconv_b, hlin_w, hlin_b,
      econv_w, econv_b, elin_w, elin_b,
      att_w1, att_b1, att_w2, hidden, essential);
  k_cheb_fc<<<NB, 256, 0, stream>>>(de, hidden, essential, gc_w, gc_b, fc_w, fc_b, zmat);
  k_bnstats<<<NC, 256, 0, stream>>>(zmat, bn_g, bn_b, bnp);
  k_bn_out<<<NB, 64, 0, stream>>>(zmat, bnp, fc4_w, fc4_b, (float*)d_out);
}

// Round 2
// 545.485 us; speedup vs baseline: 2.2040x; 2.2040x over previous
//
#include <hip/hip_runtime.h>
#include <math.h>

#define NB    1024
#define NC    62
#define NBAND 5
#define NOUT  16
#define NHID  10

// =====================================================================
// Kernel A: gate-cancelled SPD.
//   _gate: relu(g*x) = g*relu(x) since g=softmax>0.
//   _spd:  cov/trace cancels g^2 and 1/(c-1), so
//   com[b,k] = 0.5*(N(relu(pcc_t)) + N(relu(A))) + 1e-5*I,
//   N(X) = Xc^T Xc / ||Xc||_F^2,  Xc = X - rowmean(X).
//   conv_w / conv_b / the softmax gate are dead.
// XCD swizzle: the 5 bands of one b read interleaved stride-5 pcc lines;
// keep them on one XCD's L2 (5120 % 8 == 0 -> simple bijective remap).
// =====================================================================
__global__ __launch_bounds__(256) void k_spd(
    const float* __restrict__ pcc, const float* __restrict__ Aadj,
    float* __restrict__ com) {
  const int bk = (blockIdx.x & 7) * 640 + (blockIdx.x >> 3);  // 0..5119
  const int b = bk / NBAND, k = bk % NBAND;
  __shared__ __align__(16) float Xc[NC * 64];   // stride 64, cols 62/63 zero
  __shared__ float red[256];
  __shared__ float rowmean[64];
  const int tid = threadIdx.x;
  const int j = tid >> 2, q = tid & 3;

  float acc0[16], acc1[16];

  auto process = [&](int src, float (&acc)[16]) -> float {
    for (int t = tid; t < NC * 64; t += 256) {
      const int i = t >> 6, jj = t & 63;
      float v = 0.f;
      if (jj < NC) {
        v = (src == 0) ? pcc[((b * NC + i) * NC + jj) * NBAND + k]
                       : Aadj[((b * NBAND + k) * NC + i) * NC + jj];
        v = fmaxf(v, 0.f);
      }
      Xc[t] = v;
    }
    __syncthreads();
    float ps = 0.f;
    if (j < NC) {
#pragma unroll
      for (int u = 0; u < 16; ++u) ps += Xc[j * 64 + q * 16 + u];
    }
    red[tid] = ps;
    __syncthreads();
    if (tid < NC)
      rowmean[tid] = (red[tid * 4] + red[tid * 4 + 1] + red[tid * 4 + 2] + red[tid * 4 + 3]) * (1.f / NC);
    __syncthreads();
    float sq = 0.f;
    if (j < NC) {
      const float m = rowmean[j];
#pragma unroll
      for (int u = 0; u < 16; ++u) {
        const int l = q * 16 + u;
        if (l < NC) {
          const float v = Xc[j * 64 + l] - m;
          Xc[j * 64 + l] = v;
          sq += v * v;
        }
      }
    }
    red[tid] = sq;
    __syncthreads();
    for (int s = 128; s > 0; s >>= 1) {
      if (tid < s) red[tid] += red[tid + s];
      __syncthreads();
    }
    const float tra = red[0];
#pragma unroll
    for (int u = 0; u < 16; ++u) acc[u] = 0.f;
    for (int i = 0; i < NC; ++i) {
      const float xj = Xc[i * 64 + j];
      const float4 v0 = *reinterpret_cast<const float4*>(&Xc[i * 64 + q * 16 + 0]);
      const float4 v1 = *reinterpret_cast<const float4*>(&Xc[i * 64 + q * 16 + 4]);
      const float4 v2 = *reinterpret_cast<const float4*>(&Xc[i * 64 + q * 16 + 8]);
      const float4 v3 = *reinterpret_cast<const float4*>(&Xc[i * 64 + q * 16 + 12]);
      acc[0]  += xj * v0.x; acc[1]  += xj * v0.y; acc[2]  += xj * v0.z; acc[3]  += xj * v0.w;
      acc[4]  += xj * v1.x; acc[5]  += xj * v1.y; acc[6]  += xj * v1.z; acc[7]  += xj * v1.w;
      acc[8]  += xj * v2.x; acc[9]  += xj * v2.y; acc[10] += xj * v2.z; acc[11] += xj * v2.w;
      acc[12] += xj * v3.x; acc[13] += xj * v3.y; acc[14] += xj * v3.z; acc[15] += xj * v3.w;
    }
    __syncthreads();
    return tra;
  };

  const float tra0 = process(0, acc0);
  const float tra1 = process(1, acc1);

  if (j < NC) {
    const float s0 = 0.5f / tra0, s1 = 0.5f / tra1;
    const int base = (bk * NC + j) * NC;
#pragma unroll
    for (int u = 0; u < 16; ++u) {
      const int l = q * 16 + u;
      if (l < NC) {
        float v = acc0[u] * s0 + acc1[u] * s1;
        if (l == j) v += 1e-5f;
        com[base + l] = v;
      }
    }
  }
}

// =====================================================================
// Kernel B1: per (b, k, br) block: z tile GEMM + sigmoid, then the
// attention scorer as 620 parallel (i,h) tasks. Writes scores only.
//   z[i][o] = sigmoid(cw[k]*(com[i,:].lw[o,:]) + cb[k]*rsum[o] + lb[o])
//   score[i] = sum_h w2[h]*tanh(sum_c z[i][c]*w1[h][c] + b1[h])
// =====================================================================
__global__ __launch_bounds__(256) void k_branch_score(
    const float* __restrict__ com,
    const float* __restrict__ hconv_w, const float* __restrict__ hconv_b,
    const float* __restrict__ hlin_w,  const float* __restrict__ hlin_b,
    const float* __restrict__ econv_w, const float* __restrict__ econv_b,
    const float* __restrict__ elin_w,  const float* __restrict__ elin_b,
    const float* __restrict__ att_w1,  const float* __restrict__ att_b1,
    const float* __restrict__ att_w2,
    float* __restrict__ scoreG) {
  const int bid = (blockIdx.x & 7) * 1280 + (blockIdx.x >> 3);  // 0..10239
  const int br = bid & 1, bk = bid >> 1;      // br pairs share the com tile
  const int b = bk / NBAND, k = bk % NBAND;

  const float* __restrict__ cw = br ? econv_w : hconv_w;
  const float* __restrict__ cb = br ? econv_b : hconv_b;
  const float* __restrict__ lw = br ? elin_w : hlin_w;
  const float* __restrict__ lb = br ? elin_b : hlin_b;

  __shared__ float comS[NC * NC];                     // 15376 B
  __shared__ __align__(16) float lwTS[NC * 64];       // 15872 B, [c][o]
  __shared__ float zS[NC * NC];                       // 15376 B
  __shared__ float w1S[NHID * NC];                    // 2480 B
  __shared__ float partS[NC * 12];                    // 2976 B
  __shared__ float rsumS[64], lbS[64];
  __shared__ float b1S[16], w2S[16];
  __shared__ float cwk, cbk;

  const int tid = threadIdx.x;
  for (int t = tid; t < NC * NC; t += 256) {
    comS[t] = com[bk * (NC * NC) + t];
    const int o = t / NC, c = t % NC;
    lwTS[c * 64 + o] = lw[t];
  }
  for (int t = tid; t < NHID * NC; t += 256) w1S[t] = att_w1[t];
  if (tid < NC) lbS[tid] = lb[tid];
  if (tid < NHID) { b1S[tid] = att_b1[tid]; w2S[tid] = att_w2[tid]; }
  if (tid == 0) { cwk = cw[k]; cbk = cb[k]; }
  __syncthreads();
  if (tid < NC) {
    float s = 0.f;
#pragma unroll
    for (int c = 0; c < NC; ++c) s += lwTS[c * 64 + tid];
    rsumS[tid] = s;
  }
  __syncthreads();

  const int j = tid >> 2, q = tid & 3;
  float accz[16];
#pragma unroll
  for (int u = 0; u < 16; ++u) accz[u] = 0.f;
  if (j < NC) {
    for (int c = 0; c < NC; ++c) {
      const float a = comS[j * NC + c];
      const float4 v0 = *reinterpret_cast<const float4*>(&lwTS[c * 64 + q * 16 + 0]);
      const float4 v1 = *reinterpret_cast<const float4*>(&lwTS[c * 64 + q * 16 + 4]);
      const float4 v2 = *reinterpret_cast<const float4*>(&lwTS[c * 64 + q * 16 + 8]);
      const float4 v3 = *reinterpret_cast<const float4*>(&lwTS[c * 64 + q * 16 + 12]);
      accz[0]  += a * v0.x; accz[1]  += a * v0.y; accz[2]  += a * v0.z; accz[3]  += a * v0.w;
      accz[4]  += a * v1.x; accz[5]  += a * v1.y; accz[6]  += a * v1.z; accz[7]  += a * v1.w;
      accz[8]  += a * v2.x; accz[9]  += a * v2.y; accz[10] += a * v2.z; accz[11] += a * v2.w;
      accz[12] += a * v3.x; accz[13] += a * v3.y; accz[14] += a * v3.z; accz[15] += a * v3.w;
    }
#pragma unroll
    for (int u = 0; u < 16; ++u) {
      const int o = q * 16 + u;
      if (o < NC) {
        const float zv = cwk * accz[u] + cbk * rsumS[o] + lbS[o];
        zS[j * NC + o] = 1.f / (1.f + __expf(-zv));
      }
    }
  }
  __syncthreads();
  for (int t = tid; t < NC * NHID; t += 256) {
    const int i = t / NHID, h = t % NHID;
    float a = b1S[h];
    for (int c = 0; c < NC; ++c) a += zS[i * NC + c] * w1S[h * NC + c];
    partS[i * 12 + h] = w2S[h] * tanhf(a);
  }
  __syncthreads();
  if (tid < NC) {
    float s = 0.f;
#pragma unroll
    for (int h = 0; h < NHID; ++h) s += partS[tid * 12 + h];
    scoreG[(b * 2 + br) * (NBAND * NC) + k * NC + tid] = s;
  }
}

// =====================================================================
// Kernel B2: per (b, br) block: softmax over bands -> beta, then
// recompute z per band fully in registers and accumulate beta*z.
// No z materialization anywhere.
// =====================================================================
__global__ __launch_bounds__(256) void k_attn_combine(
    const float* __restrict__ com, const float* __restrict__ scoreG,
    const float* __restrict__ hconv_w, const float* __restrict__ hconv_b,
    const float* __restrict__ hlin_w,  const float* __restrict__ hlin_b,
    const float* __restrict__ econv_w, const float* __restrict__ econv_b,
    const float* __restrict__ elin_w,  const float* __restrict__ elin_b,
    float* __restrict__ hiddenO, float* __restrict__ essentialO) {
  const int bid = (blockIdx.x & 7) * 256 + (blockIdx.x >> 3);  // 0..2047
  const int b = bid >> 1, br = bid & 1;

  const float* __restrict__ cw = br ? econv_w : hconv_w;
  const float* __restrict__ cb = br ? econv_b : hconv_b;
  const float* __restrict__ lw = br ? elin_w : hlin_w;
  const float* __restrict__ lb = br ? elin_b : hlin_b;
  float* __restrict__ outp = br ? essentialO : hiddenO;

  __shared__ float comS[NC * NC];                 // 15376 B
  __shared__ __align__(16) float lwTS[NC * 64];   // 15872 B
  __shared__ float betaS[NBAND * 64];
  __shared__ float rsumS[64], lbS[64];
  __shared__ float cwS[8], cbS[8];

  const int tid = threadIdx.x;
  for (int t = tid; t < NC * NC; t += 256) {
    const int o = t / NC, c = t % NC;
    lwTS[c * 64 + o] = lw[t];
  }
  if (tid < NC) lbS[tid] = lb[tid];
  if (tid < NBAND) { cwS[tid] = cw[tid]; cbS[tid] = cb[tid]; }
  if (tid < NC) {
    const int base = (b * 2 + br) * (NBAND * NC) + tid;
    float sc[NBAND], m = -1e30f;
#pragma unroll
    for (int k = 0; k < NBAND; ++k) { sc[k] = scoreG[base + k * NC]; m = fmaxf(m, sc[k]); }
    float s = 0.f;
#pragma unroll
    for (int k = 0; k < NBAND; ++k) { sc[k] = __expf(sc[k] - m); s += sc[k]; }
    const float inv = 1.f / s;
#pragma unroll
    for (int k = 0; k < NBAND; ++k) betaS[k * 64 + tid] = sc[k] * inv;
  }
  __syncthreads();
  if (tid < NC) {
    float s = 0.f;
#pragma unroll
    for (int c = 0; c < NC; ++c) s += lwTS[c * 64 + tid];
    rsumS[tid] = s;
  }

  const int j = tid >> 2, q = tid & 3;
  float acc[16];
#pragma unroll
  for (int u = 0; u < 16; ++u) acc[u] = 0.f;

  for (int k = 0; k < NBAND; ++k) {
    __syncthreads();   // previous iteration's comS reads done (also covers rsumS/beta first time)
    for (int t = tid; t < NC * NC; t += 256) comS[t] = com[(b * NBAND + k) * (NC * NC) + t];
    __syncthreads();
    if (j < NC) {
      float accz[16];
#pragma unroll
      for (int u = 0; u < 16; ++u) accz[u] = 0.f;
      for (int c = 0; c < NC; ++c) {
        const float a = comS[j * NC + c];
        const float4 v0 = *reinterpret_cast<const float4*>(&lwTS[c * 64 + q * 16 + 0]);
        const float4 v1 = *reinterpret_cast<const float4*>(&lwTS[c * 64 + q * 16 + 4]);
        const float4 v2 = *reinterpret_cast<const float4*>(&lwTS[c * 64 + q * 16 + 8]);
        const float4 v3 = *reinterpret_cast<const float4*>(&lwTS[c * 64 + q * 16 + 12]);
        accz[0]  += a * v0.x; accz[1]  += a * v0.y; accz[2]  += a * v0.z; accz[3]  += a * v0.w;
        accz[4]  += a * v1.x; accz[5]  += a * v1.y; accz[6]  += a * v1.z; accz[7]  += a * v1.w;
        accz[8]  += a * v2.x; accz[9]  += a * v2.y; accz[10] += a * v2.z; accz[11] += a * v2.w;
        accz[12] += a * v3.x; accz[13] += a * v3.y; accz[14] += a * v3.z; accz[15] += a * v3.w;
      }
      const float bw = betaS[k * 64 + j];
      const float ck = cwS[k], dk = cbS[k];
#pragma unroll
      for (int u = 0; u < 16; ++u) {
        const int o = q * 16 + u;
        if (o < NC) {
          const float zv = ck * accz[u] + dk * rsumS[o] + lbS[o];
          acc[u] += bw / (1.f + __expf(-zv));
        }
      }
    }
  }
  if (j < NC) {
#pragma unroll
    for (int u = 0; u < 16; ++u) {
      const int o = q * 16 + u;
      if (o < NC) outp[b * (NC * NC) + j * NC + o] = acc[u];
    }
  }
}

// =====================================================================
// Kernel C: Chebyshev GCN (both adjacencies, shared de@gc_w), feature,
// and the 992->62 FC. wnorm = exp(w)/exp(w) = 1 exactly; relu((h+e)/2)
// is a no-op on relu'd h,e.
// =====================================================================
__global__ __launch_bounds__(256) void k_cheb_fc(
    const float* __restrict__ de, const float* __restrict__ hidden,
    const float* __restrict__ essential, const float* __restrict__ gc_w,
    const float* __restrict__ gc_b, const float* __restrict__ fc_w,
    const float* __restrict__ fc_b, float* __restrict__ zmat) {
  const int b = blockIdx.x;
  __shared__ float hidS[NC * NC], essS[NC * NC];
  __shared__ float t0S[NC * NOUT], t1S[NC * NOUT];
  __shared__ float featS[NC * NOUT];
  __shared__ float deS[NC * NBAND];
  __shared__ float red2[256];
  const int tid = threadIdx.x;

  for (int t = tid; t < NC * NBAND; t += 256) deS[t] = de[b * NC * NBAND + t];
  for (int t = tid; t < NC * NC; t += 256) {
    hidS[t] = hidden[b * NC * NC + t];
    essS[t] = essential[b * NC * NC + t];
  }
  __syncthreads();
  for (int t = tid; t < NC * NOUT; t += 256) {
    const int i = t / NOUT, f = t % NOUT;
    float a0 = gc_b[f];
    float a1 = 0.f;
#pragma unroll
    for (int qq = 0; qq < NBAND; ++qq) {
      const float d = deS[i * NBAND + qq];
      a0 += d * gc_w[qq * NOUT + f];
      a1 += d * gc_w[(NBAND + qq) * NOUT + f];
    }
    t0S[t] = a0;
    t1S[t] = a1;
  }
  __syncthreads();
  for (int t = tid; t < NC * NOUT; t += 256) {
    const int i = t / NOUT, f = t % NOUT;
    float sh = 0.f, se = 0.f;
    for (int jj = 0; jj < NC; ++jj) {
      const float t1 = t1S[jj * NOUT + f];
      sh += hidS[i * NC + jj] * t1;
      se += essS[i * NC + jj] * t1;
    }
    const float gb1 = gc_b[NOUT + f];
    const float h = fmaxf(t0S[t] + sh + gb1, 0.f);
    const float e = fmaxf(t0S[t] + se + gb1, 0.f);
    featS[t] = 0.5f * (h + e);
  }
  __syncthreads();
  {
    const int n = tid >> 2, q = tid & 3;
    float p = 0.f;
    if (n < NC) {
      const float* fw = fc_w + n * (NC * NOUT) + q * 248;
      const float* fs = featS + q * 248;
      for (int m = 0; m < 248; ++m) p += fs[m] * fw[m];
    }
    red2[tid] = p;
    __syncthreads();
    if (tid < NC) {
      const float z = red2[tid * 4] + red2[tid * 4 + 1] + red2[tid * 4 + 2] + red2[tid * 4 + 3] + fc_b[tid];
      zmat[b * NC + tid] = z;
    }
  }
}

// =====================================================================
// Kernel D1: batch-norm statistics (training-mode batch stats, ddof=0).
// =====================================================================
__global__ __launch_bounds__(256) void k_bnstats(
    const float* __restrict__ zmat, const float* __restrict__ bn_g,
    const float* __restrict__ bn_b, float* __restrict__ bnp) {
  const int n = blockIdx.x;
  __shared__ float rs[256], rq[256];
  const int tid = threadIdx.x;
  float s = 0.f, sq = 0.f;
  for (int r = tid; r < NB; r += 256) {
    const float v = zmat[r * NC + n];
    s += v;
    sq += v * v;
  }
  rs[tid] = s; rq[tid] = sq;
  __syncthreads();
  for (int st = 128; st > 0; st >>= 1) {
    if (tid < st) { rs[tid] += rs[tid + st]; rq[tid] += rq[tid + st]; }
    __syncthreads();
  }
  if (tid == 0) {
    const float mean = rs[0] * (1.f / NB);
    const float var = rq[0] * (1.f / NB) - mean * mean;
    const float sc = bn_g[n] * rsqrtf(var + 1e-5f);
    bnp[2 * n] = sc;
    bnp[2 * n + 1] = bn_b[n] - mean * sc;
  }
}

// =====================================================================
// Kernel D2: apply BN + sigmoid -> output1; 62->2 FC -> output.
// =====================================================================
__global__ __launch_bounds__(64) void k_bn_out(
    const float* __restrict__ zmat, const float* __restrict__ bnp,
    const float* __restrict__ fc4_w, const float* __restrict__ fc4_b,
    float* __restrict__ out) {
  const int b = blockIdx.x;
  const int lane = threadIdx.x;
  float o1 = 0.f;
  if (lane < NC) {
    float z = zmat[b * NC + lane];
    z = z * bnp[2 * lane] + bnp[2 * lane + 1];
    o1 = 1.f / (1.f + __expf(-z));
    out[b * NC + lane] = o1;
  }
  float p0 = (lane < NC) ? o1 * fc4_w[lane] : 0.f;
  float p1 = (lane < NC) ? o1 * fc4_w[NC + lane] : 0.f;
#pragma unroll
  for (int off = 32; off > 0; off >>= 1) {
    p0 += __shfl_down(p0, off, 64);
    p1 += __shfl_down(p1, off, 64);
  }
  if (lane == 0) {
    out[NB * NC + b * 2 + 0] = p0 + fc4_b[0];
    out[NB * NC + b * 2 + 1] = p1 + fc4_b[1];
  }
}

extern "C" void kernel_launch(void* const* d_in, const int* in_sizes, int n_in,
                              void* d_out, int out_size, void* d_ws, size_t ws_size,
                              hipStream_t stream) {
  const float* de      = (const float*)d_in[0];
  const float* pcc     = (const float*)d_in[1];
  const float* Aadj    = (const float*)d_in[2];
  // d_in[3] conv_w, d_in[4] conv_b: dead (gate cancels in trace-normalized SPD)
  const float* hconv_w = (const float*)d_in[5];
  const float* hconv_b = (const float*)d_in[6];
  const float* hlin_w  = (const float*)d_in[7];
  const float* hlin_b  = (const float*)d_in[8];
  const float* econv_w = (const float*)d_in[9];
  const float* econv_b = (const float*)d_in[10];
  const float* elin_w  = (const float*)d_in[11];
  const float* elin_b  = (const float*)d_in[12];
  const float* att_w1  = (const float*)d_in[13];
  const float* att_b1  = (const float*)d_in[14];
  const float* att_w2  = (const float*)d_in[15];
  const float* gc_w    = (const float*)d_in[16];
  const float* gc_b    = (const float*)d_in[17];
  // d_in[18] wpar: wnorm = exp(w)/exp(w) = 1 exactly for 1-element wpar
  const float* fc_w    = (const float*)d_in[19];
  const float* fc_b    = (const float*)d_in[20];
  const float* bn_g    = (const float*)d_in[21];
  const float* bn_b    = (const float*)d_in[22];
  const float* fc4_w   = (const float*)d_in[23];
  const float* fc4_b   = (const float*)d_in[24];

  float* ws        = (float*)d_ws;
  float* com       = ws;                                 // 19,681,280
  float* hidden    = com + (size_t)NB * NBAND * NC * NC; //  3,936,256
  float* essential = hidden + (size_t)NB * NC * NC;      //  3,936,256
  float* zmat      = essential + (size_t)NB * NC * NC;   //     63,488
  float* bnp       = zmat + (size_t)NB * NC;             //        124
  float* scoreG    = bnp + 128;                          //    634,880
  // total ~113 MB of workspace

  k_spd<<<NB * NBAND, 256, 0, stream>>>(pcc, Aadj, com);
  k_branch_score<<<NB * 2 * NBAND, 256, 0, stream>>>(com,
      hconv_w, hconv_b, hlin_w, hlin_b,
      econv_w, econv_b, elin_w, elin_b,
      att_w1, att_b1, att_w2, scoreG);
  k_attn_combine<<<NB * 2, 256, 0, stream>>>(com, scoreG,
      hconv_w, hconv_b, hlin_w, hlin_b,
      econv_w, econv_b, elin_w, elin_b, hidden, essential);
  k_cheb_fc<<<NB, 256, 0, stream>>>(de, hidden, essential, gc_w, gc_b, fc_w, fc_b, zmat);
  k_bnstats<<<NC, 256, 0, stream>>>(zmat, bn_g, bn_b, bnp);
  k_bn_out<<<NB, 64, 0, stream>>>(zmat, bnp, fc4_w, fc4_b, (float*)d_out);
}

// Round 3
// 313.452 us; speedup vs baseline: 3.8356x; 1.7402x over previous
//
#include <hip/hip_runtime.h>
#include <math.h>

#define NB    1024
#define NC    62
#define NBAND 5
#define NOUT  16
#define NHID  10
#define XSTR  68   // Xc row stride: 68 mod 32 = 4 -> row-phase bank conflicts 16-way -> 2-way (free)

// =====================================================================
// Kernel A: gate-cancelled SPD.
//   relu(softmax(s)*x) = g*relu(x), and cov/trace cancels g^2 and 1/(c-1):
//   com[b,k] = 0.5*(N(relu(pcc_t)) + N(relu(A))) + 1e-5*I,
//   N(X) = Xc^T Xc / ||Xc||_F^2, Xc row-centered. conv_w/conv_b dead.
// Thread (j,q) owns row j, cols q*16..q*16+15. Centering in registers via
// 4-lane shuffle rowsum; trace via wave shuffle; only 3 block barriers.
// Aadj prefetched into regs under SYRK0. Block 0 epilogue: lwT / rsumG.
// =====================================================================
__global__ __launch_bounds__(256) void k_spd(
    const float* __restrict__ pcc, const float* __restrict__ Aadj,
    const float* __restrict__ hlin_w, const float* __restrict__ elin_w,
    float* __restrict__ com, float* __restrict__ lwT, float* __restrict__ rsumG) {
  const int bk = (blockIdx.x & 7) * 640 + (blockIdx.x >> 3);  // XCD swizzle, 5120%8==0
  const int b = bk / NBAND, k = bk % NBAND;
  __shared__ __align__(16) float Xc[NC * XSTR];
  __shared__ float red4[4];
  const int tid = threadIdx.x;
  const int j = tid >> 2, q = tid & 3, o0 = q * 16;
  const int wave = tid >> 6, lane = tid & 63;
  const bool act = (j < NC);

  float ld[16];

  // ---- src0 = relu(pcc[b,:,:,k]) : row-per-group load
#pragma unroll
  for (int u = 0; u < 16; ++u) ld[u] = 0.f;
  if (act) {
    const float* src = pcc + ((size_t)(b * NC + j) * NC + o0) * NBAND + k;
#pragma unroll
    for (int u = 0; u < 16; ++u)
      if (o0 + u < NC) ld[u] = fmaxf(src[u * NBAND], 0.f);
  }
  float rs = 0.f;
#pragma unroll
  for (int u = 0; u < 16; ++u) rs += ld[u];
  rs += __shfl_xor(rs, 1, 64);
  rs += __shfl_xor(rs, 2, 64);
  const float m0 = rs * (1.f / NC);
  float sq = 0.f;
  if (act) {
#pragma unroll
    for (int u = 0; u < 16; ++u) {
      const float cv = (o0 + u < NC) ? (ld[u] - m0) : 0.f;
      Xc[j * XSTR + o0 + u] = cv;
      sq += cv * cv;
    }
  }
#pragma unroll
  for (int off = 1; off < 64; off <<= 1) sq += __shfl_xor(sq, off, 64);
  if (lane == 0) red4[wave] = sq;

  // prefetch src1 = Aadj[b,k] rows into regs (landing hidden under SYRK0)
#pragma unroll
  for (int u = 0; u < 16; ++u) ld[u] = 0.f;
  if (act) {
    const float* src = Aadj + ((size_t)(b * NBAND + k) * NC + j) * NC + o0;
#pragma unroll
    for (int u = 0; u < 16; ++u)
      if (o0 + u < NC) ld[u] = src[u];
  }
  __syncthreads();   // (1) Xc0 + red4 ready

  // ---- SYRK0: acc0[u] = sum_i Xc[i][j]*Xc[i][o0+u]
  float acc0[16];
#pragma unroll
  for (int u = 0; u < 16; ++u) acc0[u] = 0.f;
  for (int i = 0; i < NC; ++i) {
    const float xj = Xc[i * XSTR + j];
    const float4 v0 = *reinterpret_cast<const float4*>(&Xc[i * XSTR + o0 + 0]);
    const float4 v1 = *reinterpret_cast<const float4*>(&Xc[i * XSTR + o0 + 4]);
    const float4 v2 = *reinterpret_cast<const float4*>(&Xc[i * XSTR + o0 + 8]);
    const float4 v3 = *reinterpret_cast<const float4*>(&Xc[i * XSTR + o0 + 12]);
    acc0[0]  += xj * v0.x; acc0[1]  += xj * v0.y; acc0[2]  += xj * v0.z; acc0[3]  += xj * v0.w;
    acc0[4]  += xj * v1.x; acc0[5]  += xj * v1.y; acc0[6]  += xj * v1.z; acc0[7]  += xj * v1.w;
    acc0[8]  += xj * v2.x; acc0[9]  += xj * v2.y; acc0[10] += xj * v2.z; acc0[11] += xj * v2.w;
    acc0[12] += xj * v3.x; acc0[13] += xj * v3.y; acc0[14] += xj * v3.z; acc0[15] += xj * v3.w;
  }
  const float tra0 = red4[0] + red4[1] + red4[2] + red4[3];  // read BEFORE barrier (2)
  __syncthreads();   // (2) SYRK0 reads done; Xc/red4 reusable

  // ---- src1: relu + center in regs, write Xc
#pragma unroll
  for (int u = 0; u < 16; ++u) ld[u] = fmaxf(ld[u], 0.f);
  rs = 0.f;
#pragma unroll
  for (int u = 0; u < 16; ++u) rs += ld[u];
  rs += __shfl_xor(rs, 1, 64);
  rs += __shfl_xor(rs, 2, 64);
  const float m1 = rs * (1.f / NC);
  sq = 0.f;
  if (act) {
#pragma unroll
    for (int u = 0; u < 16; ++u) {
      const float cv = (o0 + u < NC) ? (ld[u] - m1) : 0.f;
      Xc[j * XSTR + o0 + u] = cv;
      sq += cv * cv;
    }
  }
#pragma unroll
  for (int off = 1; off < 64; off <<= 1) sq += __shfl_xor(sq, off, 64);
  if (lane == 0) red4[wave] = sq;
  __syncthreads();   // (3) Xc1 + red4 ready

  float acc1[16];
#pragma unroll
  for (int u = 0; u < 16; ++u) acc1[u] = 0.f;
  for (int i = 0; i < NC; ++i) {
    const float xj = Xc[i * XSTR + j];
    const float4 v0 = *reinterpret_cast<const float4*>(&Xc[i * XSTR + o0 + 0]);
    const float4 v1 = *reinterpret_cast<const float4*>(&Xc[i * XSTR + o0 + 4]);
    const float4 v2 = *reinterpret_cast<const float4*>(&Xc[i * XSTR + o0 + 8]);
    const float4 v3 = *reinterpret_cast<const float4*>(&Xc[i * XSTR + o0 + 12]);
    acc1[0]  += xj * v0.x; acc1[1]  += xj * v0.y; acc1[2]  += xj * v0.z; acc1[3]  += xj * v0.w;
    acc1[4]  += xj * v1.x; acc1[5]  += xj * v1.y; acc1[6]  += xj * v1.z; acc1[7]  += xj * v1.w;
    acc1[8]  += xj * v2.x; acc1[9]  += xj * v2.y; acc1[10] += xj * v2.z; acc1[11] += xj * v2.w;
    acc1[12] += xj * v3.x; acc1[13] += xj * v3.y; acc1[14] += xj * v3.z; acc1[15] += xj * v3.w;
  }
  const float tra1 = red4[0] + red4[1] + red4[2] + red4[3];

  if (act) {
    const float s0 = 0.5f / tra0, s1 = 0.5f / tra1;
    const size_t base = ((size_t)bk * NC + j) * NC;
#pragma unroll
    for (int u = 0; u < 16; ++u) {
      const int o = o0 + u;
      if (o < NC) {
        float v = acc0[u] * s0 + acc1[u] * s1;
        if (o == j) v += 1e-5f;
        com[base + o] = v;
      }
    }
  }

  // ---- block 0 epilogue: zero-padded lw transposes + row sums for k_branch
  if (blockIdx.x == 0) {
    for (int t = tid; t < NC * 64; t += 256) {
      const int c = t >> 6, o = t & 63;
      lwT[t]           = (o < NC) ? hlin_w[o * NC + c] : 0.f;
      lwT[NC * 64 + t] = (o < NC) ? elin_w[o * NC + c] : 0.f;
    }
    if (tid < 64) {
      float sh = 0.f, se = 0.f;
      if (tid < NC) {
        for (int c = 0; c < NC; ++c) { sh += hlin_w[tid * NC + c]; se += elin_w[tid * NC + c]; }
      }
      rsumG[tid] = sh;
      rsumG[64 + tid] = se;
    }
  }
}

// =====================================================================
// Kernel B (merged): per (b,br) block, online-softmax over the 5 bands.
// Per band: z-GEMM (thread (j,q) owns z[j][q*16..]) -> sigmoid in regs ->
// scorer partials + 4-lane shuffle reduce + distributed tanh -> running
// max/denom rescale accumulation. z computed ONCE; no zS/score LDS;
// com band k+1 reg-prefetched under band k's GEMM.
// =====================================================================
__global__ __launch_bounds__(256) void k_branch(
    const float* __restrict__ com, const float* __restrict__ lwT,
    const float* __restrict__ rsumG,
    const float* __restrict__ hconv_w, const float* __restrict__ hconv_b,
    const float* __restrict__ hlin_b,
    const float* __restrict__ econv_w, const float* __restrict__ econv_b,
    const float* __restrict__ elin_b,
    const float* __restrict__ att_w1,  const float* __restrict__ att_b1,
    const float* __restrict__ att_w2,
    float* __restrict__ hiddenO, float* __restrict__ essentialO) {
  const int bid = (blockIdx.x & 7) * 256 + (blockIdx.x >> 3);  // XCD swizzle, br-pairs co-XCD
  const int b = bid >> 1, br = bid & 1;

  const float* __restrict__ cw = br ? econv_w : hconv_w;
  const float* __restrict__ cb = br ? econv_b : hconv_b;
  const float* __restrict__ lb = br ? elin_b : hlin_b;
  float* __restrict__ outp = br ? essentialO : hiddenO;

  __shared__ float comS[NC * NC];                  // 15376 B
  __shared__ __align__(16) float lwTS[NC * 64];    // 15872 B  [c][o] zero-padded
  __shared__ float w1S[NHID * 64];                 // 2560 B   [h][o] zero-padded
  __shared__ float rsumS[64], lbS[64];
  __shared__ float b1S[16], w2S[16], cwS[8], cbS[8];

  const int tid = threadIdx.x;
  const int j = tid >> 2, q = tid & 3, o0 = q * 16;
  const bool act = (j < NC);

  // coalesced, conflict-free fills (lwT pre-transposed in global)
  for (int t = tid; t < NC * 64; t += 256) lwTS[t] = lwT[br * NC * 64 + t];
  for (int t = tid; t < NHID * 64; t += 256) {
    const int h = t >> 6, c = t & 63;
    w1S[t] = (c < NC) ? att_w1[h * NC + c] : 0.f;
  }
  if (tid < 64) {
    rsumS[tid] = rsumG[br * 64 + tid];
    lbS[tid] = (tid < NC) ? lb[tid] : 0.f;
  }
  if (tid < NHID) { b1S[tid] = att_b1[tid]; w2S[tid] = att_w2[tid]; }
  if (tid < NBAND) { cwS[tid] = cw[tid]; cbS[tid] = cb[tid]; }
  {
    const float* c0 = com + (size_t)(b * NBAND) * (NC * NC);
    for (int t = tid; t < NC * NC; t += 256) comS[t] = c0[t];
  }
  __syncthreads();

  float oacc[16];
#pragma unroll
  for (int u = 0; u < 16; ++u) oacc[u] = 0.f;
  float denom = 0.f, mrun = -1e30f;

  for (int kb = 0; kb < NBAND; ++kb) {
    // prefetch next band into regs (hidden under this band's GEMM)
    float pf[16];
    if (kb < NBAND - 1) {
      const float* nb = com + (size_t)(b * NBAND + kb + 1) * (NC * NC);
#pragma unroll
      for (int w = 0; w < 16; ++w) {
        const int idx = tid + w * 256;
        pf[w] = (idx < NC * NC) ? nb[idx] : 0.f;
      }
    }

    // GEMM: accz[u] = sum_c com[j][c] * lw[o0+u][c]  (via lwT[c][o])
    float accz[16];
#pragma unroll
    for (int u = 0; u < 16; ++u) accz[u] = 0.f;
    if (act) {
      for (int c = 0; c < NC; ++c) {
        const float a = comS[j * NC + c];
        const float4 v0 = *reinterpret_cast<const float4*>(&lwTS[c * 64 + o0 + 0]);
        const float4 v1 = *reinterpret_cast<const float4*>(&lwTS[c * 64 + o0 + 4]);
        const float4 v2 = *reinterpret_cast<const float4*>(&lwTS[c * 64 + o0 + 8]);
        const float4 v3 = *reinterpret_cast<const float4*>(&lwTS[c * 64 + o0 + 12]);
        accz[0]  += a * v0.x; accz[1]  += a * v0.y; accz[2]  += a * v0.z; accz[3]  += a * v0.w;
        accz[4]  += a * v1.x; accz[5]  += a * v1.y; accz[6]  += a * v1.z; accz[7]  += a * v1.w;
        accz[8]  += a * v2.x; accz[9]  += a * v2.y; accz[10] += a * v2.z; accz[11] += a * v2.w;
        accz[12] += a * v3.x; accz[13] += a * v3.y; accz[14] += a * v3.z; accz[15] += a * v3.w;
      }
    }
    // sigmoid (rsumS/lbS zero-padded, defined for all lanes)
    const float ck = cwS[kb], dk = cbS[kb];
    float z[16];
#pragma unroll
    for (int u = 0; u < 16; ++u) {
      const float zv = ck * accz[u] + dk * rsumS[o0 + u] + lbS[o0 + u];
      z[u] = 1.f / (1.f + __expf(-zv));
    }
    // scorer: p[h] = sum_c z[j][c]*w1[h][c] (w1S pad cols 0 kill o>=62 terms)
    float p[NHID];
#pragma unroll
    for (int h = 0; h < NHID; ++h) {
      float a = 0.f;
#pragma unroll
      for (int u = 0; u < 16; ++u) a += z[u] * w1S[h * 64 + o0 + u];
      a += __shfl_xor(a, 1, 64);
      a += __shfl_xor(a, 2, 64);
      p[h] = a;
    }
    // distributed tanh across the 4-lane group
    float sp = 0.f;
#pragma unroll
    for (int mm = 0; mm < 3; ++mm) {
      const int h = q + 4 * mm;
      if (h < NHID) sp += w2S[h] * tanhf(p[h] + b1S[h]);
    }
    sp += __shfl_xor(sp, 1, 64);
    sp += __shfl_xor(sp, 2, 64);
    const float s = sp;   // uniform within group

    // online softmax accumulation (exact reorder of softmax-weighted sum)
    const float nm = fmaxf(mrun, s);
    const float f = __expf(mrun - nm), e = __expf(s - nm);
    denom = denom * f + e;
#pragma unroll
    for (int u = 0; u < 16; ++u) oacc[u] = oacc[u] * f + e * z[u];
    mrun = nm;

    __syncthreads();   // all reads of comS done
    if (kb < NBAND - 1) {
#pragma unroll
      for (int w = 0; w < 16; ++w) {
        const int idx = tid + w * 256;
        if (idx < NC * NC) comS[idx] = pf[w];
      }
      __syncthreads();
    }
  }

  if (act) {
    const float inv = 1.f / denom;
    const size_t base = (size_t)b * (NC * NC) + j * NC;
#pragma unroll
    for (int u = 0; u < 16; ++u) {
      const int o = o0 + u;
      if (o < NC) outp[base + o] = oacc[u] * inv;
    }
  }
}

// =====================================================================
// Kernel C: Chebyshev GCN (both adjacencies, shared de@gc_w), feature,
// and the 992->62 FC. wnorm == 1 exactly; relu((h+e)/2) no-op on relu'd h,e.
// =====================================================================
__global__ __launch_bounds__(256) void k_cheb_fc(
    const float* __restrict__ de, const float* __restrict__ hidden,
    const float* __restrict__ essential, const float* __restrict__ gc_w,
    const float* __restrict__ gc_b, const float* __restrict__ fc_w,
    const float* __restrict__ fc_b, float* __restrict__ zmat) {
  const int b = blockIdx.x;
  __shared__ float hidS[NC * NC], essS[NC * NC];
  __shared__ float t0S[NC * NOUT], t1S[NC * NOUT];
  __shared__ float featS[NC * NOUT];
  __shared__ float deS[NC * NBAND];
  __shared__ float red2[256];
  const int tid = threadIdx.x;

  for (int t = tid; t < NC * NBAND; t += 256) deS[t] = de[b * NC * NBAND + t];
  for (int t = tid; t < NC * NC; t += 256) {
    hidS[t] = hidden[b * NC * NC + t];
    essS[t] = essential[b * NC * NC + t];
  }
  __syncthreads();
  for (int t = tid; t < NC * NOUT; t += 256) {
    const int i = t / NOUT, f = t % NOUT;
    float a0 = gc_b[f];
    float a1 = 0.f;
#pragma unroll
    for (int qq = 0; qq < NBAND; ++qq) {
      const float d = deS[i * NBAND + qq];
      a0 += d * gc_w[qq * NOUT + f];
      a1 += d * gc_w[(NBAND + qq) * NOUT + f];
    }
    t0S[t] = a0;
    t1S[t] = a1;
  }
  __syncthreads();
  for (int t = tid; t < NC * NOUT; t += 256) {
    const int i = t / NOUT, f = t % NOUT;
    float sh = 0.f, se = 0.f;
    for (int jj = 0; jj < NC; ++jj) {
      const float t1 = t1S[jj * NOUT + f];
      sh += hidS[i * NC + jj] * t1;
      se += essS[i * NC + jj] * t1;
    }
    const float gb1 = gc_b[NOUT + f];
    const float h = fmaxf(t0S[t] + sh + gb1, 0.f);
    const float e = fmaxf(t0S[t] + se + gb1, 0.f);
    featS[t] = 0.5f * (h + e);
  }
  __syncthreads();
  {
    const int n = tid >> 2, qq = tid & 3;
    float p = 0.f;
    if (n < NC) {
      const float* fw = fc_w + n * (NC * NOUT) + qq * 248;
      const float* fs = featS + qq * 248;
      for (int m = 0; m < 248; ++m) p += fs[m] * fw[m];
    }
    red2[tid] = p;
    __syncthreads();
    if (tid < NC) {
      const float z = red2[tid * 4] + red2[tid * 4 + 1] + red2[tid * 4 + 2] + red2[tid * 4 + 3] + fc_b[tid];
      zmat[b * NC + tid] = z;
    }
  }
}

// =====================================================================
// Kernel D1: batch-norm statistics (training-mode batch stats, ddof=0).
// =====================================================================
__global__ __launch_bounds__(256) void k_bnstats(
    const float* __restrict__ zmat, const float* __restrict__ bn_g,
    const float* __restrict__ bn_b, float* __restrict__ bnp) {
  const int n = blockIdx.x;
  __shared__ float rs[256], rq[256];
  const int tid = threadIdx.x;
  float s = 0.f, sq = 0.f;
  for (int r = tid; r < NB; r += 256) {
    const float v = zmat[r * NC + n];
    s += v;
    sq += v * v;
  }
  rs[tid] = s; rq[tid] = sq;
  __syncthreads();
  for (int st = 128; st > 0; st >>= 1) {
    if (tid < st) { rs[tid] += rs[tid + st]; rq[tid] += rq[tid + st]; }
    __syncthreads();
  }
  if (tid == 0) {
    const float mean = rs[0] * (1.f / NB);
    const float var = rq[0] * (1.f / NB) - mean * mean;
    const float sc = bn_g[n] * rsqrtf(var + 1e-5f);
    bnp[2 * n] = sc;
    bnp[2 * n + 1] = bn_b[n] - mean * sc;
  }
}

// =====================================================================
// Kernel D2: apply BN + sigmoid -> output1; 62->2 FC -> output.
// =====================================================================
__global__ __launch_bounds__(64) void k_bn_out(
    const float* __restrict__ zmat, const float* __restrict__ bnp,
    const float* __restrict__ fc4_w, const float* __restrict__ fc4_b,
    float* __restrict__ out) {
  const int b = blockIdx.x;
  const int lane = threadIdx.x;
  float o1 = 0.f;
  if (lane < NC) {
    float z = zmat[b * NC + lane];
    z = z * bnp[2 * lane] + bnp[2 * lane + 1];
    o1 = 1.f / (1.f + __expf(-z));
    out[b * NC + lane] = o1;
  }
  float p0 = (lane < NC) ? o1 * fc4_w[lane] : 0.f;
  float p1 = (lane < NC) ? o1 * fc4_w[NC + lane] : 0.f;
#pragma unroll
  for (int off = 32; off > 0; off >>= 1) {
    p0 += __shfl_down(p0, off, 64);
    p1 += __shfl_down(p1, off, 64);
  }
  if (lane == 0) {
    out[NB * NC + b * 2 + 0] = p0 + fc4_b[0];
    out[NB * NC + b * 2 + 1] = p1 + fc4_b[1];
  }
}

extern "C" void kernel_launch(void* const* d_in, const int* in_sizes, int n_in,
                              void* d_out, int out_size, void* d_ws, size_t ws_size,
                              hipStream_t stream) {
  const float* de      = (const float*)d_in[0];
  const float* pcc     = (const float*)d_in[1];
  const float* Aadj    = (const float*)d_in[2];
  // d_in[3] conv_w, d_in[4] conv_b: dead (gate cancels in trace-normalized SPD)
  const float* hconv_w = (const float*)d_in[5];
  const float* hconv_b = (const float*)d_in[6];
  const float* hlin_w  = (const float*)d_in[7];
  const float* hlin_b  = (const float*)d_in[8];
  const float* econv_w = (const float*)d_in[9];
  const float* econv_b = (const float*)d_in[10];
  const float* elin_w  = (const float*)d_in[11];
  const float* elin_b  = (const float*)d_in[12];
  const float* att_w1  = (const float*)d_in[13];
  const float* att_b1  = (const float*)d_in[14];
  const float* att_w2  = (const float*)d_in[15];
  const float* gc_w    = (const float*)d_in[16];
  const float* gc_b    = (const float*)d_in[17];
  // d_in[18] wpar: wnorm = exp(w)/exp(w) = 1 exactly for 1-element wpar
  const float* fc_w    = (const float*)d_in[19];
  const float* fc_b    = (const float*)d_in[20];
  const float* bn_g    = (const float*)d_in[21];
  const float* bn_b    = (const float*)d_in[22];
  const float* fc4_w   = (const float*)d_in[23];
  const float* fc4_b   = (const float*)d_in[24];

  float* ws        = (float*)d_ws;
  float* com       = ws;                                 // 19,681,280
  float* hidden    = com + (size_t)NB * NBAND * NC * NC; //  3,936,256
  float* essential = hidden + (size_t)NB * NC * NC;      //  3,936,256
  float* zmat      = essential + (size_t)NB * NC * NC;   //     63,488
  float* bnp       = zmat + (size_t)NB * NC;             //        128
  float* lwT       = bnp + 128;                          //      7,936 (2 x 62 x 64, zero-padded)
  float* rsumG     = lwT + 2 * NC * 64;                  //        128
  // total ~111 MB of workspace

  k_spd<<<NB * NBAND, 256, 0, stream>>>(pcc, Aadj, hlin_w, elin_w, com, lwT, rsumG);
  k_branch<<<NB * 2, 256, 0, stream>>>(com, lwT, rsumG,
      hconv_w, hconv_b, hlin_b,
      econv_w, econv_b, elin_b,
      att_w1, att_b1, att_w2, hidden, essential);
  k_cheb_fc<<<NB, 256, 0, stream>>>(de, hidden, essential, gc_w, gc_b, fc_w, fc_b, zmat);
  k_bnstats<<<NC, 256, 0, stream>>>(zmat, bn_g, bn_b, bnp);
  k_bn_out<<<NB, 64, 0, stream>>>(zmat, bnp, fc4_w, fc4_b, (float*)d_out);
}